// Round 10
// baseline (31.185 us; speedup 1.0000x reference)
//
#include <hip/hip_runtime.h>
#include <math.h>

// u: (B=8, T=64, NY=256, NX=256) f32. Residual: (B, 62, NY, NX), center t+1.
// x/y zero-padded, t not padded. Output: sqrt(sum(res^2)).
#define B_    8
#define T_    64
#define NY_   256
#define NX_   256
#define PS_   (NY_ * NX_)

// One wave = YB consecutive y-rows x full x-row (64 lanes x float4 = 256).
// YB=8 cuts L1-miss traffic/residual-row: (YB+2)/YB halo factor 1.5 -> 1.25.
// Measured ceiling across R1/R7/R9: ~16 B/cyc/CU miss fill (~9.8 TB/s chip).
#define YB_     8
#define NSTRIP  (NY_ / YB_)                 // 32 strips
#define TCHUNKS 8                           // 7 chunks of 8 t-steps + 1 of 6
#define NWAVES  (B_ * NSTRIP * TCHUNKS)     // 2048 waves = 8/CU
#define NTHREADS 256
#define NBLOCKS  (NWAVES / 4)               // 512 blocks (8 XCDs x 64)

__device__ __forceinline__ float4 loadf4(const float* p) { return *(const float4*)p; }

// Depth-1 rolling planes (R6-proven). Loads issue batched (10 rows), consumed
// in load order. Do NOT register-pipeline an extra plane set (R4: spills),
// do NOT fuse finalize (R5: remat), do NOT barrier-couple waves (R8).
template <int LEN>
__device__ __forceinline__ float strip_accum(const float* __restrict__ u,
                                             int b, int ys, int t0, int lane) {
    const float a   = 0.04f;                        // 1/DH^2
    const float kdt = 250000.0f / 4840000.0f;       // (1/DT^2)/C^2
    const float k2  = 2.0f * kdt - 4.0f * a;        // coeff of center

    const int y0 = ys * YB_;
    const float m0 = (ys > 0)           ? 1.0f : 0.0f;   // top halo row validity
    const float m5 = (ys < NSTRIP - 1)  ? 1.0f : 0.0f;   // bottom halo row validity
    const float xl = (lane > 0)  ? 1.0f : 0.0f;
    const float xr = (lane < 63) ? 1.0f : 0.0f;

    int yoff[YB_ + 2];
    #pragma unroll
    for (int j = 0; j < YB_ + 2; ++j) {
        int y = y0 - 1 + j;
        y = y < 0 ? 0 : (y > NY_ - 1 ? NY_ - 1 : y);
        yoff[j] = y * NX_;
    }

    const float* pl = u + ((size_t)b * T_ + t0) * PS_ + lane * 4;

    float4 tm[YB_], c[YB_ + 2];
    #pragma unroll
    for (int i = 0; i < YB_; ++i) tm[i] = loadf4(pl + yoff[i + 1]);
    const float* p1 = pl + PS_;
    #pragma unroll
    for (int j = 0; j < YB_ + 2; ++j) c[j] = loadf4(p1 + yoff[j]);
    c[0].x *= m0; c[0].y *= m0; c[0].z *= m0; c[0].w *= m0;
    c[YB_+1].x *= m5; c[YB_+1].y *= m5; c[YB_+1].z *= m5; c[YB_+1].w *= m5;

    float acc = 0.0f;
    const float* pn = pl + 2 * PS_;
    #pragma unroll
    for (int k = 0; k < LEN; ++k) {
        float4 nn[YB_ + 2];
        #pragma unroll
        for (int j = 0; j < YB_ + 2; ++j) nn[j] = loadf4(pn + yoff[j]);
        nn[0].x *= m0; nn[0].y *= m0; nn[0].z *= m0; nn[0].w *= m0;
        nn[YB_+1].x *= m5; nn[YB_+1].y *= m5; nn[YB_+1].z *= m5; nn[YB_+1].w *= m5;

        #pragma unroll
        for (int i = 0; i < YB_; ++i) {
            float4 ctr = c[i + 1], up = c[i], dn = c[i + 2];
            float4 t = tm[i], nf = nn[i + 1];
            float cl = __shfl_up(ctr.w, 1, 64) * xl;
            float cr = __shfl_down(ctr.x, 1, 64) * xr;

            {
                float s2 = cl + ctr.y + up.x + dn.x;
                float r = fmaf(s2, a, fmaf(t.x + nf.x, -kdt, ctr.x * k2));
                acc = fmaf(r, r, acc);
            }
            {
                float s2 = ctr.x + ctr.z + up.y + dn.y;
                float r = fmaf(s2, a, fmaf(t.y + nf.y, -kdt, ctr.y * k2));
                acc = fmaf(r, r, acc);
            }
            {
                float s2 = ctr.y + ctr.w + up.z + dn.z;
                float r = fmaf(s2, a, fmaf(t.z + nf.z, -kdt, ctr.z * k2));
                acc = fmaf(r, r, acc);
            }
            {
                float s2 = ctr.z + cr + up.w + dn.w;
                float r = fmaf(s2, a, fmaf(t.w + nf.w, -kdt, ctr.w * k2));
                acc = fmaf(r, r, acc);
            }
        }

        #pragma unroll
        for (int i = 0; i < YB_; ++i) tm[i] = c[i + 1];
        #pragma unroll
        for (int j = 0; j < YB_ + 2; ++j) c[j] = nn[j];
        pn += PS_;
    }
    return acc;
}

// (256,2): 256-VGPR cap — generous headroom for the 28-float4 live state so the
// allocator never flips to remat/spill (R4/R5 cliff). Grid gives 8 waves/CU.
__global__ __launch_bounds__(NTHREADS, 2)
void pinn_residual_partial(const float* __restrict__ u, float* __restrict__ partial) {
    const int lane = threadIdx.x & 63;
    const int w    = threadIdx.x >> 6;

    // XCD-aware mapping (proven: FETCH 123->82 MB): b = bid&7 pins each batch
    // (16.8 MB) to one XCD's L2. 512 blocks = 8 x 64, bijective.
    const int b     = blockIdx.x & 7;
    const int inner = blockIdx.x >> 3;             // 0..63
    const int ys    = (inner & 7) * 4 + w;         // 4 consecutive strips per block
    const int tc    = inner >> 3;                  // 0..7
    const int t0    = tc * 8;

    float s;
    if (tc < TCHUNKS - 1) s = strip_accum<8>(u, b, ys, t0, lane);
    else                  s = strip_accum<6>(u, b, ys, t0, lane);

    #pragma unroll
    for (int off = 32; off > 0; off >>= 1)
        s += __shfl_down(s, off, 64);

    __shared__ float lds[NTHREADS / 64];
    if (lane == 0) lds[w] = s;
    __syncthreads();
    if (threadIdx.x == 0) {
        float bs = lds[0] + lds[1] + lds[2] + lds[3];
        partial[blockIdx.x] = bs;   // every slot written every launch
    }
}

__global__ __launch_bounds__(NTHREADS)
void pinn_finalize(const float* __restrict__ partial, float* __restrict__ out) {
    float s = 0.0f;
    for (int i = threadIdx.x; i < NBLOCKS; i += NTHREADS)
        s += partial[i];
    #pragma unroll
    for (int off = 32; off > 0; off >>= 1)
        s += __shfl_down(s, off, 64);
    __shared__ float lds[NTHREADS / 64];
    int lane = threadIdx.x & 63;
    int wid  = threadIdx.x >> 6;
    if (lane == 0) lds[wid] = s;
    __syncthreads();
    if (threadIdx.x == 0) {
        float bs = 0.0f;
        #pragma unroll
        for (int q = 0; q < NTHREADS / 64; ++q) bs += lds[q];
        out[0] = sqrtf(bs);
    }
}

extern "C" void kernel_launch(void* const* d_in, const int* in_sizes, int n_in,
                              void* d_out, int out_size, void* d_ws, size_t ws_size,
                              hipStream_t stream) {
    const float* u = (const float*)d_in[0];
    float* partial = (float*)d_ws;              // NBLOCKS floats = 2 KiB scratch
    float* out     = (float*)d_out;

    pinn_residual_partial<<<NBLOCKS, NTHREADS, 0, stream>>>(u, partial);
    pinn_finalize<<<1, NTHREADS, 0, stream>>>(partial, out);
}